// Round 1
// 1097.766 us; speedup vs baseline: 1.0616x; 1.0616x over previous
//
#include <hip/hip_runtime.h>
#include <hip/hip_bf16.h>

// R3: vocab GEMM rework.
// - out_w is pre-converted fp32->bf16 (RNE) once per launch (cvtw_k), final
//   rmsnorm emits bf16 directly (rmsbf_k).
// - gemm_vocab: pure-bf16 128x128 tile, BK=64, global_load_lds width-16
//   staging (no VALU convert, no reg round-trip), linear LDS, 2-barrier loop
//   (m97 structure). Block remap: XCD-chunked + M-fastest so the 16 M-tiles
//   sharing a B-panel run adjacently on one XCD -> B fetched ~once from HBM.
// Everything else (layers, split-bf16 GEMMs for h-path) unchanged: top-2 MoE
// routing requires h to match the fp32 reference closely.

#define BT   2048
#define TSEQ 1024
#define CDIM 512
#define NKVD 128
#define NEXP 8
#define NVOC 32000

using bf16 = __hip_bfloat16;
typedef __attribute__((ext_vector_type(8))) short short8;
typedef __attribute__((ext_vector_type(4))) float floatx4;

// ---------------------------------------------------------------- helpers

// truncation split: v = hi + lo + r, |r| <= 2^-17 |v|
__device__ inline void split8(const float* __restrict__ src, short8& hi, short8& lo) {
    float4 f0 = *reinterpret_cast<const float4*>(src);
    float4 f1 = *reinterpret_cast<const float4*>(src + 4);
    float v[8] = {f0.x, f0.y, f0.z, f0.w, f1.x, f1.y, f1.z, f1.w};
    #pragma unroll
    for (int j = 0; j < 8; ++j) {
        unsigned u = __builtin_bit_cast(unsigned, v[j]);
        hi[j] = (short)(u >> 16);
        float hf = __builtin_bit_cast(float, u & 0xffff0000u);
        float r = v[j] - hf;
        lo[j] = (short)(__builtin_bit_cast(unsigned, r) >> 16);
    }
}

// RTN f32 -> bf16 x8
__device__ inline short8 cvt8(const float* __restrict__ src) {
    float4 f0 = *reinterpret_cast<const float4*>(src);
    float4 f1 = *reinterpret_cast<const float4*>(src + 4);
    float v[8] = {f0.x, f0.y, f0.z, f0.w, f1.x, f1.y, f1.z, f1.w};
    short8 h;
    #pragma unroll
    for (int j = 0; j < 8; ++j) {
        unsigned u = __builtin_bit_cast(unsigned, v[j]);
        u = u + 0x7fffu + ((u >> 16) & 1u);
        h[j] = (short)(u >> 16);
    }
    return h;
}

__device__ inline unsigned short tobf(float f) {
    unsigned u = __builtin_bit_cast(unsigned, f);
    u = u + 0x7fffu + ((u >> 16) & 1u);
    return (unsigned short)(u >> 16);
}

// async global->LDS, 16B per lane; lds base must be wave-uniform
__device__ inline void gload_lds16(const void* g, void* lds) {
    __builtin_amdgcn_global_load_lds(
        (const __attribute__((address_space(1))) unsigned int*)g,
        (__attribute__((address_space(3))) unsigned int*)lds, 16, 0, 0);
}

__global__ void embed_k(const int* __restrict__ ids, const float* __restrict__ tok,
                        const float* __restrict__ pos, float* __restrict__ h) {
    int n = blockIdx.x, t = threadIdx.x;
    int id = ids[n];
    int p = n & (TSEQ - 1);
    for (int c = t; c < CDIM; c += 256)
        h[(long)n * CDIM + c] = tok[(long)id * CDIM + c] + pos[(long)p * CDIM + c];
}

__global__ void rms_k(const float* __restrict__ x, const float* __restrict__ w,
                      float* __restrict__ out) {
    int n = blockIdx.x, t = threadIdx.x;
    const float* xr = x + (long)n * CDIM;
    float v0 = xr[t], v1 = xr[t + 256];
    float ss = v0 * v0 + v1 * v1;
    #pragma unroll
    for (int o = 32; o > 0; o >>= 1) ss += __shfl_down(ss, o);
    __shared__ float red[4];
    if ((t & 63) == 0) red[t >> 6] = ss;
    __syncthreads();
    float tot = red[0] + red[1] + red[2] + red[3];
    float rstd = 1.0f / sqrtf(tot * (1.0f / CDIM) + 1e-6f);
    out[(long)n * CDIM + t]       = v0 * rstd * w[t];
    out[(long)n * CDIM + t + 256] = v1 * rstd * w[t + 256];
}

// final rmsnorm, bf16 output (RNE, matches the cvt8 path numerically)
__global__ void rmsbf_k(const float* __restrict__ x, const float* __restrict__ w,
                        unsigned short* __restrict__ out) {
    int n = blockIdx.x, t = threadIdx.x;
    const float* xr = x + (long)n * CDIM;
    float v0 = xr[t], v1 = xr[t + 256];
    float ss = v0 * v0 + v1 * v1;
    #pragma unroll
    for (int o = 32; o > 0; o >>= 1) ss += __shfl_down(ss, o);
    __shared__ float red[4];
    if ((t & 63) == 0) red[t >> 6] = ss;
    __syncthreads();
    float tot = red[0] + red[1] + red[2] + red[3];
    float rstd = 1.0f / sqrtf(tot * (1.0f / CDIM) + 1e-6f);
    out[(long)n * CDIM + t]       = tobf(v0 * rstd * w[t]);
    out[(long)n * CDIM + t + 256] = tobf(v1 * rstd * w[t + 256]);
}

// fp32 -> bf16 bulk convert, 8 elems/thread, exact-size launch
__global__ void cvtw_k(const float* __restrict__ src, unsigned short* __restrict__ dst) {
    long i = ((long)blockIdx.x * 256 + threadIdx.x) * 8;
    short8 h = cvt8(src + i);
    *reinterpret_cast<short8*>(dst + i) = h;
}

// ---------------------------------------------------------------- GEMM
// D[M,N] (+)= A[M,K] * B[N,K]^T, fp32 in/out, split-bf16 MFMA inside.
template<int BM, int BN, bool SPLIT, bool ACCUM>
__global__ __launch_bounds__(256, 2)
void gemm_f32(const float* __restrict__ A, const float* __restrict__ B,
              float* __restrict__ D, int M, int N, int Kd,
              int lda, int ldb, int ldd,
              long aBatch, long bBatch, int dDiv, long dOuter, long dInner)
{
    constexpr int BK = 64;
    constexpr int WM = BM / 2, WN = BN / 2;
    constexpr int TM = WM / 16, TN = WN / 16;
    constexpr int LDP = BK + 8;
    __shared__ bf16 AsH[BM][LDP];
    __shared__ bf16 BsH[BN][LDP];
    __shared__ bf16 AsL[SPLIT ? BM : 1][SPLIT ? LDP : 1];
    __shared__ bf16 BsL[SPLIT ? BN : 1][SPLIT ? LDP : 1];

    int z = blockIdx.z;
    const float* Ap = A + (long)z * aBatch;
    const float* Bp = B + (long)z * bBatch;
    long dOff = (long)(z / dDiv) * dOuter + (long)(z % dDiv) * dInner;
    int bm = blockIdx.y * BM;
    int bn = blockIdx.x * BN;
    int tid = threadIdx.x;
    int wave = tid >> 6, lane = tid & 63;
    int wm = (wave >> 1) * WM, wn = (wave & 1) * WN;
    int lrow = lane & 15, quad = lane >> 4;

    floatx4 acc[TM][TN];
    #pragma unroll
    for (int i = 0; i < TM; ++i)
        #pragma unroll
        for (int j = 0; j < TN; ++j)
            acc[i][j] = (floatx4){0.f, 0.f, 0.f, 0.f};

    constexpr int ACH = BM * BK / (8 * 256);
    constexpr int BCH = BN * BK / (8 * 256);

    for (int k0 = 0; k0 < Kd; k0 += BK) {
        #pragma unroll
        for (int i = 0; i < ACH; ++i) {
            int c = tid + i * 256;
            int r = c >> 3, c8 = (c & 7) << 3;
            const float* src = Ap + (long)(bm + r) * lda + k0 + c8;
            if constexpr (SPLIT) {
                short8 hi, lo;
                split8(src, hi, lo);
                *reinterpret_cast<short8*>(&AsH[r][c8]) = hi;
                *reinterpret_cast<short8*>(&AsL[r][c8]) = lo;
            } else {
                *reinterpret_cast<short8*>(&AsH[r][c8]) = cvt8(src);
            }
        }
        #pragma unroll
        for (int i = 0; i < BCH; ++i) {
            int c = tid + i * 256;
            int r = c >> 3, c8 = (c & 7) << 3;
            const float* src = Bp + (long)(bn + r) * ldb + k0 + c8;
            if constexpr (SPLIT) {
                short8 hi, lo;
                split8(src, hi, lo);
                *reinterpret_cast<short8*>(&BsH[r][c8]) = hi;
                *reinterpret_cast<short8*>(&BsL[r][c8]) = lo;
            } else {
                *reinterpret_cast<short8*>(&BsH[r][c8]) = cvt8(src);
            }
        }
        __syncthreads();
        #pragma unroll
        for (int kc = 0; kc < BK / 32; ++kc) {
            short8 ah[TM], bh[TN], al[TM], bl[TN];
            #pragma unroll
            for (int i = 0; i < TM; ++i) {
                ah[i] = *reinterpret_cast<const short8*>(&AsH[wm + i * 16 + lrow][kc * 32 + quad * 8]);
                if constexpr (SPLIT)
                    al[i] = *reinterpret_cast<const short8*>(&AsL[wm + i * 16 + lrow][kc * 32 + quad * 8]);
            }
            #pragma unroll
            for (int j = 0; j < TN; ++j) {
                bh[j] = *reinterpret_cast<const short8*>(&BsH[wn + j * 16 + lrow][kc * 32 + quad * 8]);
                if constexpr (SPLIT)
                    bl[j] = *reinterpret_cast<const short8*>(&BsL[wn + j * 16 + lrow][kc * 32 + quad * 8]);
            }
            #pragma unroll
            for (int i = 0; i < TM; ++i)
                #pragma unroll
                for (int j = 0; j < TN; ++j) {
                    acc[i][j] = __builtin_amdgcn_mfma_f32_16x16x32_bf16(ah[i], bh[j], acc[i][j], 0, 0, 0);
                    if constexpr (SPLIT) {
                        acc[i][j] = __builtin_amdgcn_mfma_f32_16x16x32_bf16(ah[i], bl[j], acc[i][j], 0, 0, 0);
                        acc[i][j] = __builtin_amdgcn_mfma_f32_16x16x32_bf16(al[i], bh[j], acc[i][j], 0, 0, 0);
                    }
                }
        }
        __syncthreads();
    }

    // C/D: col = lane&15, row = quad*4 + reg  [m89-verified]
    #pragma unroll
    for (int i = 0; i < TM; ++i)
        #pragma unroll
        for (int j = 0; j < TN; ++j) {
            int row = bm + wm + i * 16 + quad * 4;
            int col = bn + wn + j * 16 + lrow;
            #pragma unroll
            for (int r = 0; r < 4; ++r) {
                long idx = dOff + (long)(row + r) * ldd + col;
                if constexpr (ACCUM) D[idx] += acc[i][j][r];
                else                 D[idx]  = acc[i][j][r];
            }
        }
}

// ---------------------------------------------------------------- vocab GEMM
// D[2048,32000] = A[2048,512]bf16 * B[32000,512]bf16^T, fp32 out.
// 128x128 tile, BK=64, global_load_lds staging, linear LDS, 2-barrier loop.
// Grid: 4000 linear blocks; remap = XCD-chunked (nwg%8==0 -> bijective) with
// M fastest inside each chunk so consecutive blocks on an XCD share a B-panel.
__global__ __launch_bounds__(256)
void gemm_vocab(const bf16* __restrict__ A, const bf16* __restrict__ B,
                float* __restrict__ D)
{
    constexpr int BK = 64;
    __shared__ __align__(16) bf16 As[128 * BK];
    __shared__ __align__(16) bf16 Bs[128 * BK];

    int id  = blockIdx.x;                      // 0..3999
    int swz = (id & 7) * 500 + (id >> 3);      // XCD gets contiguous 500-chunk
    int bm  = (swz & 15) << 7;                 // 16 M-tiles, fastest
    int bn  = (swz >> 4) << 7;                 // 250 N-tiles

    int tid = threadIdx.x;
    int wave = tid >> 6, lane = tid & 63;
    int wm = (wave >> 1) << 6, wn = (wave & 1) << 6;
    int lrow = lane & 15, quad = lane >> 4;

    floatx4 acc[4][4];
    #pragma unroll
    for (int i = 0; i < 4; ++i)
        #pragma unroll
        for (int j = 0; j < 4; ++j)
            acc[i][j] = (floatx4){0.f, 0.f, 0.f, 0.f};

    const bf16* a0 = A + (long)bm * CDIM;
    const bf16* b0 = B + (long)bn * CDIM;

    for (int k0 = 0; k0 < CDIM; k0 += BK) {
        // stage 16KB A + 16KB B: per wave 4 chunks of 1KB each
        #pragma unroll
        for (int i = 0; i < 4; ++i) {
            int pb = wave * 4096 + i * 1024;   // wave-uniform LDS byte base
            int p  = pb + lane * 16;           // this lane's byte in tile
            int r  = p >> 7;                   // row (row = 128B)
            int c  = (p & 127) >> 1;           // col in elements
            gload_lds16(a0 + (long)r * CDIM + k0 + c, (char*)As + pb);
            gload_lds16(b0 + (long)r * CDIM + k0 + c, (char*)Bs + pb);
        }
        __syncthreads();   // drains vmcnt before barrier
        #pragma unroll
        for (int kc = 0; kc < BK / 32; ++kc) {
            short8 ah[4], bh[4];
            #pragma unroll
            for (int i = 0; i < 4; ++i) {
                ah[i] = *reinterpret_cast<const short8*>(As + (wm + i * 16 + lrow) * BK + kc * 32 + quad * 8);
                bh[i] = *reinterpret_cast<const short8*>(Bs + (wn + i * 16 + lrow) * BK + kc * 32 + quad * 8);
            }
            #pragma unroll
            for (int i = 0; i < 4; ++i)
                #pragma unroll
                for (int j = 0; j < 4; ++j)
                    acc[i][j] = __builtin_amdgcn_mfma_f32_16x16x32_bf16(ah[i], bh[j], acc[i][j], 0, 0, 0);
        }
        __syncthreads();
    }

    #pragma unroll
    for (int i = 0; i < 4; ++i)
        #pragma unroll
        for (int j = 0; j < 4; ++j) {
            int row = bm + wm + i * 16 + quad * 4;
            int col = bn + wn + j * 16 + lrow;
            #pragma unroll
            for (int r = 0; r < 4; ++r)
                D[(long)(row + r) * NVOC + col] = acc[i][j][r];
        }
}

// ---------------------------------------------------------------- attention

__global__ void pack_k(const float* __restrict__ Qb, const float* __restrict__ Kb,
                       const float* __restrict__ Vb, float* __restrict__ Qp,
                       float* __restrict__ Kp, float* __restrict__ Vt) {
    long id = (long)blockIdx.x * 256 + threadIdx.x;  // 16*1024*64
    int d = id & 63;
    int t = (id >> 6) & (TSEQ - 1);
    int z = id >> 16;
    int b = z >> 3, hh = z & 7, kvh = hh >> 2;
    long src = (long)(b * TSEQ + t);
    Qp[id] = Qb[src * CDIM + hh * 64 + d];
    Kp[id] = Kb[src * NKVD + kvh * 64 + d];
    Vt[((long)z * 64 + d) * TSEQ + t] = Vb[src * NKVD + kvh * 64 + d];
}

// causal scaled softmax, in place: S[z][q][:] -> probabilities (0 above diag)
__global__ void softmax_k(float* __restrict__ S) {
    int q = blockIdx.x, z = blockIdx.y, t = threadIdx.x;
    float* srow = S + ((long)z * TSEQ + q) * TSEQ;
    int len = q + 1;
    const float sc = 0.125f;
    float mx = -3.0e38f;
    for (int k = t; k < len; k += 256) mx = fmaxf(mx, srow[k]);
    #pragma unroll
    for (int o = 32; o > 0; o >>= 1) mx = fmaxf(mx, __shfl_down(mx, o));
    __shared__ float red[8];
    if ((t & 63) == 0) red[t >> 6] = mx;
    __syncthreads();
    mx = fmaxf(fmaxf(red[0], red[1]), fmaxf(red[2], red[3]));
    float sum = 0.f;
    for (int k = t; k < len; k += 256) sum += __expf((srow[k] - mx) * sc);
    #pragma unroll
    for (int o = 32; o > 0; o >>= 1) sum += __shfl_down(sum, o);
    if ((t & 63) == 0) red[4 + (t >> 6)] = sum;
    __syncthreads();
    float inv = 1.0f / (red[4] + red[5] + red[6] + red[7]);
    for (int k = t; k < TSEQ; k += 256) {
        float p = (k < len) ? __expf((srow[k] - mx) * sc) * inv : 0.0f;
        srow[k] = p;
    }
}

// ---------------------------------------------------------------- MoE

__global__ void route_k(const float* __restrict__ h, const float* __restrict__ w,
                        const float* __restrict__ gw, float* __restrict__ comb) {
    int n = blockIdx.x, t = threadIdx.x;
    const float* xr = h + (long)n * CDIM;
    float v0 = xr[t], v1 = xr[t + 256];
    float ss = v0 * v0 + v1 * v1;
    #pragma unroll
    for (int o = 32; o > 0; o >>= 1) ss += __shfl_down(ss, o);
    __shared__ float rr[4];
    __shared__ float ac[4][8];
    if ((t & 63) == 0) rr[t >> 6] = ss;
    __syncthreads();
    float tot = rr[0] + rr[1] + rr[2] + rr[3];
    float rstd = 1.0f / sqrtf(tot * (1.0f / CDIM) + 1e-6f);
    float x0 = v0 * rstd * w[t], x1 = v1 * rstd * w[t + 256];
    float pe[NEXP];
    #pragma unroll
    for (int e = 0; e < NEXP; ++e)
        pe[e] = x0 * gw[e * CDIM + t] + x1 * gw[e * CDIM + t + 256];
    #pragma unroll
    for (int e = 0; e < NEXP; ++e)
        #pragma unroll
        for (int o = 32; o > 0; o >>= 1) pe[e] += __shfl_down(pe[e], o);
    if ((t & 63) == 0)
        #pragma unroll
        for (int e = 0; e < NEXP; ++e) ac[t >> 6][e] = pe[e];
    __syncthreads();
    if (t == 0) {
        float lg[NEXP];
        #pragma unroll
        for (int e = 0; e < NEXP; ++e) lg[e] = ac[0][e] + ac[1][e] + ac[2][e] + ac[3][e];
        int i1 = 0; float l1 = lg[0];
        #pragma unroll
        for (int e = 1; e < NEXP; ++e) if (lg[e] > l1) { l1 = lg[e]; i1 = e; }
        int i2 = -1; float l2 = -3.0e38f;
        #pragma unroll
        for (int e = 0; e < NEXP; ++e) if (e != i1 && lg[e] > l2) { l2 = lg[e]; i2 = e; }
        float e2 = __expf(l2 - l1);
        float dnm = 1.0f + e2;
        float* cr = comb + (long)n * NEXP;
        #pragma unroll
        for (int e = 0; e < NEXP; ++e) cr[e] = 0.f;
        cr[i1] = 1.0f / dnm;
        cr[i2] = e2 / dnm;
    }
}

__global__ void combine_k(float* __restrict__ h, const float* __restrict__ allout,
                          const float* __restrict__ comb) {
    int n = blockIdx.x, t = threadIdx.x;
    __shared__ float cw[NEXP];
    if (t < NEXP) cw[t] = comb[(long)n * NEXP + t];
    __syncthreads();
    for (int c = t; c < CDIM; c += 256) {
        float a = h[(long)n * CDIM + c];
        #pragma unroll
        for (int e = 0; e < NEXP; ++e) {
            float wv = cw[e];
            if (wv != 0.0f) a += wv * allout[((long)e * BT + n) * CDIM + c];
        }
        h[(long)n * CDIM + c] = a;
    }
}

// ---------------------------------------------------------------- launch

extern "C" void kernel_launch(void* const* d_in, const int* in_sizes, int n_in,
                              void* d_out, int out_size, void* d_ws, size_t ws_size,
                              hipStream_t stream) {
    const int*   ids  = (const int*)d_in[0];
    const float* tok  = (const float*)d_in[1];
    const float* pos  = (const float*)d_in[2];
    const float* anw  = (const float*)d_in[3];
    const float* qw   = (const float*)d_in[4];
    const float* kw   = (const float*)d_in[5];
    const float* vw   = (const float*)d_in[6];
    const float* ow   = (const float*)d_in[7];
    const float* fnw  = (const float*)d_in[8];
    const float* gw   = (const float*)d_in[9];
    const float* ew   = (const float*)d_in[10];
    const float* finw = (const float*)d_in[11];
    const float* outw = (const float*)d_in[12];
    float* out = (float*)d_out;

    char* wsp = (char*)d_ws;
    auto alloc = [&](size_t bytes) -> char* {
        char* p = wsp;
        wsp += (bytes + 255) & ~(size_t)255;
        return p;
    };
    float* H    = (float*)alloc((size_t)BT * CDIM * 4);
    float* XN   = (float*)alloc((size_t)BT * CDIM * 4);
    float* QB   = (float*)alloc((size_t)BT * CDIM * 4);
    float* KB   = (float*)alloc((size_t)BT * NKVD * 4);
    float* VB   = (float*)alloc((size_t)BT * NKVD * 4);
    float* QP   = (float*)alloc((size_t)16 * TSEQ * 64 * 4);
    float* KP   = (float*)alloc((size_t)16 * TSEQ * 64 * 4);
    float* VT   = (float*)alloc((size_t)16 * TSEQ * 64 * 4);
    float* AOB  = (float*)alloc((size_t)BT * CDIM * 4);
    float* SS   = (float*)alloc((size_t)16 * TSEQ * TSEQ * 4);  // scores/P; reused as allout
    float* COMB = (float*)alloc((size_t)BT * NEXP * 4);

    embed_k<<<dim3(BT), dim3(256), 0, stream>>>(ids, tok, pos, H);

    for (int l = 0; l < 2; ++l) {
        const float* qwl = qw + (long)l * CDIM * CDIM;
        const float* kwl = kw + (long)l * NKVD * CDIM;
        const float* vwl = vw + (long)l * NKVD * CDIM;
        const float* owl = ow + (long)l * CDIM * CDIM;
        const float* ewl = ew + (long)l * NEXP * CDIM * CDIM;

        rms_k<<<dim3(BT), dim3(256), 0, stream>>>(H, anw + l * CDIM, XN);
        gemm_f32<128,128,true,false><<<dim3(4,16,1), dim3(256), 0, stream>>>(
            XN, qwl, QB, BT, CDIM, CDIM, CDIM, CDIM, CDIM, 0, 0, 1, 0, 0);
        gemm_f32<128,128,true,false><<<dim3(1,16,1), dim3(256), 0, stream>>>(
            XN, kwl, KB, BT, NKVD, CDIM, CDIM, CDIM, NKVD, 0, 0, 1, 0, 0);
        gemm_f32<128,128,true,false><<<dim3(1,16,1), dim3(256), 0, stream>>>(
            XN, vwl, VB, BT, NKVD, CDIM, CDIM, CDIM, NKVD, 0, 0, 1, 0, 0);
        pack_k<<<dim3(4096), dim3(256), 0, stream>>>(QB, KB, VB, QP, KP, VT);
        // S[z] = Qp[z] @ Kp[z]^T
        gemm_f32<128,128,true,false><<<dim3(8,8,16), dim3(256), 0, stream>>>(
            QP, KP, SS, TSEQ, TSEQ, 64, 64, 64, TSEQ,
            (long)TSEQ * 64, (long)TSEQ * 64, 1, (long)TSEQ * TSEQ, 0);
        softmax_k<<<dim3(TSEQ, 16), dim3(256), 0, stream>>>(SS);
        // AOB[b*T+t][h*64+d] = P[z] @ Vt[z]^T
        gemm_f32<128,64,true,false><<<dim3(1,8,16), dim3(256), 0, stream>>>(
            SS, VT, AOB, TSEQ, 64, TSEQ, TSEQ, TSEQ, CDIM,
            (long)TSEQ * TSEQ, (long)64 * TSEQ, 8, (long)TSEQ * CDIM, 64);
        // H += AOB @ o_w^T
        gemm_f32<128,128,true,true><<<dim3(4,16,1), dim3(256), 0, stream>>>(
            AOB, owl, H, BT, CDIM, CDIM, CDIM, CDIM, CDIM, 0, 0, 1, 0, 0);
        // MoE
        route_k<<<dim3(BT), dim3(256), 0, stream>>>(H, fnw + l * CDIM, gw + (long)l * NEXP * CDIM, COMB);
        rms_k<<<dim3(BT), dim3(256), 0, stream>>>(H, fnw + l * CDIM, XN);
        gemm_f32<128,128,true,false><<<dim3(4,16,8), dim3(256), 0, stream>>>(
            XN, ewl, SS, BT, CDIM, CDIM, CDIM, CDIM, CDIM,
            0, (long)CDIM * CDIM, 1, (long)BT * CDIM, 0);
        combine_k<<<dim3(BT), dim3(256), 0, stream>>>(H, SS, COMB);
    }

    // ---- final projection: bf16 path ----
    // SS (64 MB) is dead now -> reuse as bf16 out_w (32.8 MB).
    // QB (4 MB) is dead -> reuse as bf16 normalized activations (2 MB).
    unsigned short* OWB = (unsigned short*)SS;
    unsigned short* XNB = (unsigned short*)QB;
    rmsbf_k<<<dim3(BT), dim3(256), 0, stream>>>(H, finw, XNB);
    cvtw_k<<<dim3((NVOC * CDIM) / (256 * 8)), dim3(256), 0, stream>>>(outw, OWB);
    gemm_vocab<<<dim3(4000), dim3(256), 0, stream>>>((const bf16*)XNB, (const bf16*)OWB, out);
}

// Round 3
// 817.725 us; speedup vs baseline: 1.4251x; 1.3425x over previous
//
#include <hip/hip_runtime.h>
#include <hip/hip_bf16.h>

// R5 == R4 resubmit (container-level infra failure last round; source audited,
// no defect found — identical code to preserve the A/B vs R3).
// R4: causal-skip attention pipeline + occupancy fixes + vocab dbuf.
// - QK^T skips tiles strictly above the diagonal (SKIPUP); softmax only
//   writes/zeroes up to the 128-aligned tile end; PV clips K at bm+64 (KCLIP).
//   Removed work is exactly-zero contributions -> h bit-identical.
// - Q/K/V projections fused into one 64x64-tile GEMM (384 blocks).
// - PV and O-proj moved to 64x64 tiles (256 blocks each, full machine).
// - V transpose via LDS tile (coalesced both sides).
// - route_k emits the ffn-normalized activations (drops 2 rms_k launches).
// - gemm_vocab: double-buffered LDS, prefetch-next-tile before compute.
// Split-bf16 (hi+lo) GEMM math is unchanged in accumulation order, so the
// top-2 MoE routing matches the fp32 reference exactly, as before.

#define BT   2048
#define TSEQ 1024
#define CDIM 512
#define NKVD 128
#define NEXP 8
#define NVOC 32000

using bf16 = __hip_bfloat16;
typedef __attribute__((ext_vector_type(8))) short short8;
typedef __attribute__((ext_vector_type(4))) float floatx4;

// ---------------------------------------------------------------- helpers

// truncation split: v = hi + lo + r, |r| <= 2^-17 |v|
__device__ inline void split8(const float* __restrict__ src, short8& hi, short8& lo) {
    float4 f0 = *reinterpret_cast<const float4*>(src);
    float4 f1 = *reinterpret_cast<const float4*>(src + 4);
    float v[8] = {f0.x, f0.y, f0.z, f0.w, f1.x, f1.y, f1.z, f1.w};
    #pragma unroll
    for (int j = 0; j < 8; ++j) {
        unsigned u = __builtin_bit_cast(unsigned, v[j]);
        hi[j] = (short)(u >> 16);
        float hf = __builtin_bit_cast(float, u & 0xffff0000u);
        float r = v[j] - hf;
        lo[j] = (short)(__builtin_bit_cast(unsigned, r) >> 16);
    }
}

// RNE f32 -> bf16 x8
__device__ inline short8 cvt8(const float* __restrict__ src) {
    float4 f0 = *reinterpret_cast<const float4*>(src);
    float4 f1 = *reinterpret_cast<const float4*>(src + 4);
    float v[8] = {f0.x, f0.y, f0.z, f0.w, f1.x, f1.y, f1.z, f1.w};
    short8 h;
    #pragma unroll
    for (int j = 0; j < 8; ++j) {
        unsigned u = __builtin_bit_cast(unsigned, v[j]);
        u = u + 0x7fffu + ((u >> 16) & 1u);
        h[j] = (short)(u >> 16);
    }
    return h;
}

__device__ inline unsigned short tobf(float f) {
    unsigned u = __builtin_bit_cast(unsigned, f);
    u = u + 0x7fffu + ((u >> 16) & 1u);
    return (unsigned short)(u >> 16);
}

// async global->LDS, 16B per lane; lds base must be wave-uniform
__device__ inline void gload_lds16(const void* g, void* lds) {
    __builtin_amdgcn_global_load_lds(
        (const __attribute__((address_space(1))) unsigned int*)g,
        (__attribute__((address_space(3))) unsigned int*)lds, 16, 0, 0);
}

__global__ void embed_k(const int* __restrict__ ids, const float* __restrict__ tok,
                        const float* __restrict__ pos, float* __restrict__ h) {
    int n = blockIdx.x, t = threadIdx.x;
    int id = ids[n];
    int p = n & (TSEQ - 1);
    for (int c = t; c < CDIM; c += 256)
        h[(long)n * CDIM + c] = tok[(long)id * CDIM + c] + pos[(long)p * CDIM + c];
}

__global__ void rms_k(const float* __restrict__ x, const float* __restrict__ w,
                      float* __restrict__ out) {
    int n = blockIdx.x, t = threadIdx.x;
    const float* xr = x + (long)n * CDIM;
    float v0 = xr[t], v1 = xr[t + 256];
    float ss = v0 * v0 + v1 * v1;
    #pragma unroll
    for (int o = 32; o > 0; o >>= 1) ss += __shfl_down(ss, o);
    __shared__ float red[4];
    if ((t & 63) == 0) red[t >> 6] = ss;
    __syncthreads();
    float tot = red[0] + red[1] + red[2] + red[3];
    float rstd = 1.0f / sqrtf(tot * (1.0f / CDIM) + 1e-6f);
    out[(long)n * CDIM + t]       = v0 * rstd * w[t];
    out[(long)n * CDIM + t + 256] = v1 * rstd * w[t + 256];
}

// final rmsnorm, bf16 output
__global__ void rmsbf_k(const float* __restrict__ x, const float* __restrict__ w,
                        unsigned short* __restrict__ out) {
    int n = blockIdx.x, t = threadIdx.x;
    const float* xr = x + (long)n * CDIM;
    float v0 = xr[t], v1 = xr[t + 256];
    float ss = v0 * v0 + v1 * v1;
    #pragma unroll
    for (int o = 32; o > 0; o >>= 1) ss += __shfl_down(ss, o);
    __shared__ float red[4];
    if ((t & 63) == 0) red[t >> 6] = ss;
    __syncthreads();
    float tot = red[0] + red[1] + red[2] + red[3];
    float rstd = 1.0f / sqrtf(tot * (1.0f / CDIM) + 1e-6f);
    out[(long)n * CDIM + t]       = tobf(v0 * rstd * w[t]);
    out[(long)n * CDIM + t + 256] = tobf(v1 * rstd * w[t + 256]);
}

// fp32 -> bf16 bulk convert
__global__ void cvtw_k(const float* __restrict__ src, unsigned short* __restrict__ dst) {
    long i = ((long)blockIdx.x * 256 + threadIdx.x) * 8;
    short8 h = cvt8(src + i);
    *reinterpret_cast<short8*>(dst + i) = h;
}

// ---------------------------------------------------------------- GEMM
// D[M,N] (+)= A[M,K] * B[N,K]^T, fp32 in/out, split-bf16 MFMA inside.
// SKIPUP: early-exit when bn > bm (strictly-above-diagonal causal tile).
// KCLIP:  clip K loop at bm + BM (causal P rows: cols > q are exact zeros).
template<int BM, int BN, bool SPLIT, bool ACCUM, bool SKIPUP, bool KCLIP>
__global__ __launch_bounds__(256, 2)
void gemm_f32(const float* __restrict__ A, const float* __restrict__ B,
              float* __restrict__ D, int M, int N, int Kd,
              int lda, int ldb, int ldd,
              long aBatch, long bBatch, int dDiv, long dOuter, long dInner)
{
    constexpr int BK = 64;
    constexpr int WM = BM / 2, WN = BN / 2;
    constexpr int TM = WM / 16, TN = WN / 16;
    constexpr int LDP = BK + 8;
    __shared__ bf16 AsH[BM][LDP];
    __shared__ bf16 BsH[BN][LDP];
    __shared__ bf16 AsL[SPLIT ? BM : 1][SPLIT ? LDP : 1];
    __shared__ bf16 BsL[SPLIT ? BN : 1][SPLIT ? LDP : 1];

    int z = blockIdx.z;
    const float* Ap = A + (long)z * aBatch;
    const float* Bp = B + (long)z * bBatch;
    long dOff = (long)(z / dDiv) * dOuter + (long)(z % dDiv) * dInner;
    int bm = blockIdx.y * BM;
    int bn = blockIdx.x * BN;
    if constexpr (SKIPUP) { if (bn > bm) return; }
    int tid = threadIdx.x;
    int wave = tid >> 6, lane = tid & 63;
    int wm = (wave >> 1) * WM, wn = (wave & 1) * WN;
    int lrow = lane & 15, quad = lane >> 4;

    floatx4 acc[TM][TN];
    #pragma unroll
    for (int i = 0; i < TM; ++i)
        #pragma unroll
        for (int j = 0; j < TN; ++j)
            acc[i][j] = (floatx4){0.f, 0.f, 0.f, 0.f};

    constexpr int ACH = BM * BK / (8 * 256);
    constexpr int BCH = BN * BK / (8 * 256);

    int kend = KCLIP ? min(Kd, bm + BM) : Kd;

    for (int k0 = 0; k0 < kend; k0 += BK) {
        #pragma unroll
        for (int i = 0; i < ACH; ++i) {
            int c = tid + i * 256;
            int r = c >> 3, c8 = (c & 7) << 3;
            const float* src = Ap + (long)(bm + r) * lda + k0 + c8;
            if constexpr (SPLIT) {
                short8 hi, lo;
                split8(src, hi, lo);
                *reinterpret_cast<short8*>(&AsH[r][c8]) = hi;
                *reinterpret_cast<short8*>(&AsL[r][c8]) = lo;
            } else {
                *reinterpret_cast<short8*>(&AsH[r][c8]) = cvt8(src);
            }
        }
        #pragma unroll
        for (int i = 0; i < BCH; ++i) {
            int c = tid + i * 256;
            int r = c >> 3, c8 = (c & 7) << 3;
            const float* src = Bp + (long)(bn + r) * ldb + k0 + c8;
            if constexpr (SPLIT) {
                short8 hi, lo;
                split8(src, hi, lo);
                *reinterpret_cast<short8*>(&BsH[r][c8]) = hi;
                *reinterpret_cast<short8*>(&BsL[r][c8]) = lo;
            } else {
                *reinterpret_cast<short8*>(&BsH[r][c8]) = cvt8(src);
            }
        }
        __syncthreads();
        #pragma unroll
        for (int kc = 0; kc < BK / 32; ++kc) {
            short8 ah[TM], bh[TN], al[TM], bl[TN];
            #pragma unroll
            for (int i = 0; i < TM; ++i) {
                ah[i] = *reinterpret_cast<const short8*>(&AsH[wm + i * 16 + lrow][kc * 32 + quad * 8]);
                if constexpr (SPLIT)
                    al[i] = *reinterpret_cast<const short8*>(&AsL[wm + i * 16 + lrow][kc * 32 + quad * 8]);
            }
            #pragma unroll
            for (int j = 0; j < TN; ++j) {
                bh[j] = *reinterpret_cast<const short8*>(&BsH[wn + j * 16 + lrow][kc * 32 + quad * 8]);
                if constexpr (SPLIT)
                    bl[j] = *reinterpret_cast<const short8*>(&BsL[wn + j * 16 + lrow][kc * 32 + quad * 8]);
            }
            #pragma unroll
            for (int i = 0; i < TM; ++i)
                #pragma unroll
                for (int j = 0; j < TN; ++j) {
                    acc[i][j] = __builtin_amdgcn_mfma_f32_16x16x32_bf16(ah[i], bh[j], acc[i][j], 0, 0, 0);
                    if constexpr (SPLIT) {
                        acc[i][j] = __builtin_amdgcn_mfma_f32_16x16x32_bf16(ah[i], bl[j], acc[i][j], 0, 0, 0);
                        acc[i][j] = __builtin_amdgcn_mfma_f32_16x16x32_bf16(al[i], bh[j], acc[i][j], 0, 0, 0);
                    }
                }
        }
        __syncthreads();
    }

    // C/D: col = lane&15, row = quad*4 + reg  [m89-verified]
    #pragma unroll
    for (int i = 0; i < TM; ++i)
        #pragma unroll
        for (int j = 0; j < TN; ++j) {
            int row = bm + wm + i * 16 + quad * 4;
            int col = bn + wn + j * 16 + lrow;
            #pragma unroll
            for (int r = 0; r < 4; ++r) {
                long idx = dOff + (long)(row + r) * ldd + col;
                if constexpr (ACCUM) D[idx] += acc[i][j][r];
                else                 D[idx]  = acc[i][j][r];
            }
        }
}

// ---------------------------------------------------------------- fused QKV
// QKV[2048,768] = XN[2048,512] * [qw;kw;vw]^T, split-bf16, 64x64 tiles.
// grid (12, 32): bx 0-7 -> q panels, 8-9 -> k, 10-11 -> v.
__global__ __launch_bounds__(256, 2)
void gemm_qkv(const float* __restrict__ A, const float* __restrict__ Bq,
              const float* __restrict__ Bk, const float* __restrict__ Bv,
              float* __restrict__ D)
{
    constexpr int BK = 64, LDP = 72;
    __shared__ bf16 AsH[64][LDP], AsL[64][LDP];
    __shared__ bf16 BsH[64][LDP], BsL[64][LDP];

    int bx = blockIdx.x;
    const float* Bp = (bx < 8)  ? Bq + (long)bx * 64 * CDIM
                    : (bx < 10) ? Bk + (long)(bx - 8) * 64 * CDIM
                                : Bv + (long)(bx - 10) * 64 * CDIM;
    int bm = blockIdx.y * 64;
    int bn = bx * 64;
    int tid = threadIdx.x;
    int wave = tid >> 6, lane = tid & 63;
    int wm = (wave >> 1) * 32, wn = (wave & 1) * 32;
    int lrow = lane & 15, quad = lane >> 4;

    floatx4 acc[2][2];
    #pragma unroll
    for (int i = 0; i < 2; ++i)
        #pragma unroll
        for (int j = 0; j < 2; ++j)
            acc[i][j] = (floatx4){0.f, 0.f, 0.f, 0.f};

    for (int k0 = 0; k0 < CDIM; k0 += BK) {
        #pragma unroll
        for (int i = 0; i < 2; ++i) {
            int c = tid + i * 256;
            int r = c >> 3, c8 = (c & 7) << 3;
            short8 hi, lo;
            split8(A + (long)(bm + r) * CDIM + k0 + c8, hi, lo);
            *reinterpret_cast<short8*>(&AsH[r][c8]) = hi;
            *reinterpret_cast<short8*>(&AsL[r][c8]) = lo;
            split8(Bp + (long)r * CDIM + k0 + c8, hi, lo);
            *reinterpret_cast<short8*>(&BsH[r][c8]) = hi;
            *reinterpret_cast<short8*>(&BsL[r][c8]) = lo;
        }
        __syncthreads();
        #pragma unroll
        for (int kc = 0; kc < 2; ++kc) {
            short8 ah[2], al[2], bh[2], bl[2];
            #pragma unroll
            for (int i = 0; i < 2; ++i) {
                ah[i] = *reinterpret_cast<const short8*>(&AsH[wm + i * 16 + lrow][kc * 32 + quad * 8]);
                al[i] = *reinterpret_cast<const short8*>(&AsL[wm + i * 16 + lrow][kc * 32 + quad * 8]);
                bh[i] = *reinterpret_cast<const short8*>(&BsH[wn + i * 16 + lrow][kc * 32 + quad * 8]);
                bl[i] = *reinterpret_cast<const short8*>(&BsL[wn + i * 16 + lrow][kc * 32 + quad * 8]);
            }
            #pragma unroll
            for (int i = 0; i < 2; ++i)
                #pragma unroll
                for (int j = 0; j < 2; ++j) {
                    acc[i][j] = __builtin_amdgcn_mfma_f32_16x16x32_bf16(ah[i], bh[j], acc[i][j], 0, 0, 0);
                    acc[i][j] = __builtin_amdgcn_mfma_f32_16x16x32_bf16(ah[i], bl[j], acc[i][j], 0, 0, 0);
                    acc[i][j] = __builtin_amdgcn_mfma_f32_16x16x32_bf16(al[i], bh[j], acc[i][j], 0, 0, 0);
                }
        }
        __syncthreads();
    }

    #pragma unroll
    for (int i = 0; i < 2; ++i)
        #pragma unroll
        for (int j = 0; j < 2; ++j) {
            int row = bm + wm + i * 16 + quad * 4;
            int col = bn + wn + j * 16 + lrow;
            #pragma unroll
            for (int r = 0; r < 4; ++r)
                D[(long)(row + r) * 768 + col] = acc[i][j][r];
        }
}

// ---------------------------------------------------------------- vocab GEMM
// D[2048,32000] = A[2048,512]bf16 * B[32000,512]bf16^T, fp32 out.
// 128x128 tile, BK=64, global_load_lds, double-buffered LDS (prefetch next
// K-tile before computing current; one barrier per K-step).
__global__ __launch_bounds__(256)
void gemm_vocab(const bf16* __restrict__ A, const bf16* __restrict__ B,
                float* __restrict__ D)
{
    constexpr int BK = 64;
    __shared__ __align__(16) bf16 As[2][128 * BK];
    __shared__ __align__(16) bf16 Bs[2][128 * BK];

    int id  = blockIdx.x;                      // 0..3999
    int swz = (id & 7) * 500 + (id >> 3);      // XCD gets contiguous 500-chunk
    int bm  = (swz & 15) << 7;                 // 16 M-tiles, fastest
    int bn  = (swz >> 4) << 7;                 // 250 N-tiles

    int tid = threadIdx.x;
    int wave = tid >> 6, lane = tid & 63;
    int wm = (wave >> 1) << 6, wn = (wave & 1) << 6;
    int lrow = lane & 15, quad = lane >> 4;

    floatx4 acc[4][4];
    #pragma unroll
    for (int i = 0; i < 4; ++i)
        #pragma unroll
        for (int j = 0; j < 4; ++j)
            acc[i][j] = (floatx4){0.f, 0.f, 0.f, 0.f};

    const bf16* a0 = A + (long)bm * CDIM;
    const bf16* b0 = B + (long)bn * CDIM;

    auto stage = [&](int buf, int k0) {
        #pragma unroll
        for (int i = 0; i < 4; ++i) {
            int pb = wave * 4096 + i * 1024;   // wave-uniform LDS byte base
            int p  = pb + lane * 16;
            int r  = p >> 7;
            int c  = (p & 127) >> 1;
            gload_lds16(a0 + (long)r * CDIM + k0 + c, (char*)As[buf] + pb);
            gload_lds16(b0 + (long)r * CDIM + k0 + c, (char*)Bs[buf] + pb);
        }
    };

    stage(0, 0);
    __syncthreads();
    int cur = 0;
    constexpr int NT = CDIM / BK;              // 8
    for (int t = 0; t < NT; ++t) {
        if (t + 1 < NT) stage(cur ^ 1, (t + 1) * BK);
        #pragma unroll
        for (int kc = 0; kc < BK / 32; ++kc) {
            short8 ah[4], bh[4];
            #pragma unroll
            for (int i = 0; i < 4; ++i) {
                ah[i] = *reinterpret_cast<const short8*>(As[cur] + (wm + i * 16 + lrow) * BK + kc * 32 + quad * 8);
                bh[i] = *reinterpret_cast<const short8*>(Bs[cur] + (wn + i * 16 + lrow) * BK + kc * 32 + quad * 8);
            }
            #pragma unroll
            for (int i = 0; i < 4; ++i)
                #pragma unroll
                for (int j = 0; j < 4; ++j)
                    acc[i][j] = __builtin_amdgcn_mfma_f32_16x16x32_bf16(ah[i], bh[j], acc[i][j], 0, 0, 0);
        }
        __syncthreads();   // drains vmcnt (prefetch done) + lgkm; cur released
        cur ^= 1;
    }

    #pragma unroll
    for (int i = 0; i < 4; ++i)
        #pragma unroll
        for (int j = 0; j < 4; ++j) {
            int row = bm + wm + i * 16 + quad * 4;
            int col = bn + wn + j * 16 + lrow;
            #pragma unroll
            for (int r = 0; r < 4; ++r)
                D[(long)(row + r) * NVOC + col] = acc[i][j][r];
        }
}

// ---------------------------------------------------------------- attention

// Q,K pack from fused QKV buffer (ld 768)
__global__ void packqk_k(const float* __restrict__ QKV, float* __restrict__ Qp,
                         float* __restrict__ Kp) {
    long id = (long)blockIdx.x * 256 + threadIdx.x;  // 16*1024*64
    int d = id & 63;
    int t = (id >> 6) & (TSEQ - 1);
    int z = id >> 16;
    int b = z >> 3, hh = z & 7, kvh = hh >> 2;
    long src = (long)(b * TSEQ + t) * 768;
    Qp[id] = QKV[src + hh * 64 + d];
    Kp[id] = QKV[src + 512 + kvh * 64 + d];
}

// V transpose via LDS tile: Vt[z][d][t] = QKV[b*T+t][640+kvh*64+d]
__global__ void vtr_k(const float* __restrict__ QKV, float* __restrict__ Vt) {
    __shared__ float tile[64][65];
    int z = blockIdx.y, tt = blockIdx.x;
    int b = z >> 3, kvh = (z & 7) >> 2;
    int t0 = tt * 64;
    int tid = threadIdx.x;
    #pragma unroll
    for (int i = 0; i < 16; ++i) {
        int d = tid & 63, tl = i * 4 + (tid >> 6);
        tile[tl][d] = QKV[(long)(b * TSEQ + t0 + tl) * 768 + 640 + kvh * 64 + d];
    }
    __syncthreads();
    #pragma unroll
    for (int i = 0; i < 16; ++i) {
        int tl = tid & 63, d = i * 4 + (tid >> 6);
        Vt[((long)z * 64 + d) * TSEQ + t0 + tl] = tile[tl][d];
    }
}

// causal scaled softmax, in place; only writes up to the 128-aligned tile end
// (strictly-above-diagonal tiles are never computed nor read: QK^T skips them,
//  PV clips K at the 64-aligned row-tile end).
__global__ void softmax_k(float* __restrict__ S) {
    int q = blockIdx.x, z = blockIdx.y, t = threadIdx.x;
    float* srow = S + ((long)z * TSEQ + q) * TSEQ;
    int len = q + 1;
    int wend = ((q >> 7) + 1) << 7;
    const float sc = 0.125f;
    float mx = -3.0e38f;
    for (int k = t; k < len; k += 256) mx = fmaxf(mx, srow[k]);
    #pragma unroll
    for (int o = 32; o > 0; o >>= 1) mx = fmaxf(mx, __shfl_down(mx, o));
    __shared__ float red[8];
    if ((t & 63) == 0) red[t >> 6] = mx;
    __syncthreads();
    mx = fmaxf(fmaxf(red[0], red[1]), fmaxf(red[2], red[3]));
    float sum = 0.f;
    for (int k = t; k < len; k += 256) sum += __expf((srow[k] - mx) * sc);
    #pragma unroll
    for (int o = 32; o > 0; o >>= 1) sum += __shfl_down(sum, o);
    if ((t & 63) == 0) red[4 + (t >> 6)] = sum;
    __syncthreads();
    float inv = 1.0f / (red[4] + red[5] + red[6] + red[7]);
    for (int k = t; k < wend; k += 256) {
        float p = (k < len) ? __expf((srow[k] - mx) * sc) * inv : 0.0f;
        srow[k] = p;
    }
}

// ---------------------------------------------------------------- MoE

// routing + ffn rmsnorm output (xn) in one pass
__global__ void route_k(const float* __restrict__ h, const float* __restrict__ w,
                        const float* __restrict__ gw, float* __restrict__ comb,
                        float* __restrict__ xn) {
    int n = blockIdx.x, t = threadIdx.x;
    const float* xr = h + (long)n * CDIM;
    float v0 = xr[t], v1 = xr[t + 256];
    float ss = v0 * v0 + v1 * v1;
    #pragma unroll
    for (int o = 32; o > 0; o >>= 1) ss += __shfl_down(ss, o);
    __shared__ float rr[4];
    __shared__ float ac[4][8];
    if ((t & 63) == 0) rr[t >> 6] = ss;
    __syncthreads();
    float tot = rr[0] + rr[1] + rr[2] + rr[3];
    float rstd = 1.0f / sqrtf(tot * (1.0f / CDIM) + 1e-6f);
    float x0 = v0 * rstd * w[t], x1 = v1 * rstd * w[t + 256];
    xn[(long)n * CDIM + t]       = x0;
    xn[(long)n * CDIM + t + 256] = x1;
    float pe[NEXP];
    #pragma unroll
    for (int e = 0; e < NEXP; ++e)
        pe[e] = x0 * gw[e * CDIM + t] + x1 * gw[e * CDIM + t + 256];
    #pragma unroll
    for (int e = 0; e < NEXP; ++e)
        #pragma unroll
        for (int o = 32; o > 0; o >>= 1) pe[e] += __shfl_down(pe[e], o);
    if ((t & 63) == 0)
        #pragma unroll
        for (int e = 0; e < NEXP; ++e) ac[t >> 6][e] = pe[e];
    __syncthreads();
    if (t == 0) {
        float lg[NEXP];
        #pragma unroll
        for (int e = 0; e < NEXP; ++e) lg[e] = ac[0][e] + ac[1][e] + ac[2][e] + ac[3][e];
        int i1 = 0; float l1 = lg[0];
        #pragma unroll
        for (int e = 1; e < NEXP; ++e) if (lg[e] > l1) { l1 = lg[e]; i1 = e; }
        int i2 = -1; float l2 = -3.0e38f;
        #pragma unroll
        for (int e = 0; e < NEXP; ++e) if (e != i1 && lg[e] > l2) { l2 = lg[e]; i2 = e; }
        float e2 = __expf(l2 - l1);
        float dnm = 1.0f + e2;
        float* cr = comb + (long)n * NEXP;
        #pragma unroll
        for (int e = 0; e < NEXP; ++e) cr[e] = 0.f;
        cr[i1] = 1.0f / dnm;
        cr[i2] = e2 / dnm;
    }
}

__global__ void combine_k(float* __restrict__ h, const float* __restrict__ allout,
                          const float* __restrict__ comb) {
    int n = blockIdx.x, t = threadIdx.x;
    __shared__ float cw[NEXP];
    if (t < NEXP) cw[t] = comb[(long)n * NEXP + t];
    __syncthreads();
    for (int c = t; c < CDIM; c += 256) {
        float a = h[(long)n * CDIM + c];
        #pragma unroll
        for (int e = 0; e < NEXP; ++e) {
            float wv = cw[e];
            if (wv != 0.0f) a += wv * allout[((long)e * BT + n) * CDIM + c];
        }
        h[(long)n * CDIM + c] = a;
    }
}

// ---------------------------------------------------------------- launch

extern "C" void kernel_launch(void* const* d_in, const int* in_sizes, int n_in,
                              void* d_out, int out_size, void* d_ws, size_t ws_size,
                              hipStream_t stream) {
    const int*   ids  = (const int*)d_in[0];
    const float* tok  = (const float*)d_in[1];
    const float* pos  = (const float*)d_in[2];
    const float* anw  = (const float*)d_in[3];
    const float* qw   = (const float*)d_in[4];
    const float* kw   = (const float*)d_in[5];
    const float* vw   = (const float*)d_in[6];
    const float* ow   = (const float*)d_in[7];
    const float* fnw  = (const float*)d_in[8];
    const float* gw   = (const float*)d_in[9];
    const float* ew   = (const float*)d_in[10];
    const float* finw = (const float*)d_in[11];
    const float* outw = (const float*)d_in[12];
    float* out = (float*)d_out;

    char* wsp = (char*)d_ws;
    auto alloc = [&](size_t bytes) -> char* {
        char* p = wsp;
        wsp += (bytes + 255) & ~(size_t)255;
        return p;
    };
    float* H    = (float*)alloc((size_t)BT * CDIM * 4);
    float* XN   = (float*)alloc((size_t)BT * CDIM * 4);
    float* QKV  = (float*)alloc((size_t)BT * 768 * 4);
    float* QP   = (float*)alloc((size_t)16 * TSEQ * 64 * 4);
    float* KP   = (float*)alloc((size_t)16 * TSEQ * 64 * 4);
    float* VT   = (float*)alloc((size_t)16 * TSEQ * 64 * 4);
    float* AOB  = (float*)alloc((size_t)BT * CDIM * 4);
    float* SS   = (float*)alloc((size_t)16 * TSEQ * TSEQ * 4);  // scores/P
    float* AOUT = (float*)alloc((size_t)NEXP * BT * CDIM * 4);  // expert outs
    float* COMB = (float*)alloc((size_t)BT * NEXP * 4);

    embed_k<<<dim3(BT), dim3(256), 0, stream>>>(ids, tok, pos, H);

    for (int l = 0; l < 2; ++l) {
        const float* qwl = qw + (long)l * CDIM * CDIM;
        const float* kwl = kw + (long)l * NKVD * CDIM;
        const float* vwl = vw + (long)l * NKVD * CDIM;
        const float* owl = ow + (long)l * CDIM * CDIM;
        const float* ewl = ew + (long)l * NEXP * CDIM * CDIM;

        rms_k<<<dim3(BT), dim3(256), 0, stream>>>(H, anw + l * CDIM, XN);
        gemm_qkv<<<dim3(12, 32), dim3(256), 0, stream>>>(XN, qwl, kwl, vwl, QKV);
        packqk_k<<<dim3(4096), dim3(256), 0, stream>>>(QKV, QP, KP);
        vtr_k<<<dim3(16, 16), dim3(256), 0, stream>>>(QKV, VT);
        // S[z] = Qp[z] @ Kp[z]^T  (skip strictly-above-diagonal tiles)
        gemm_f32<128,128,true,false,true,false><<<dim3(8,8,16), dim3(256), 0, stream>>>(
            QP, KP, SS, TSEQ, TSEQ, 64, 64, 64, TSEQ,
            (long)TSEQ * 64, (long)TSEQ * 64, 1, (long)TSEQ * TSEQ, 0);
        softmax_k<<<dim3(TSEQ, 16), dim3(256), 0, stream>>>(SS);
        // AOB[b*T+t][h*64+d] = P[z] @ Vt[z]^T  (clip K at causal limit)
        gemm_f32<64,64,true,false,false,true><<<dim3(1,16,16), dim3(256), 0, stream>>>(
            SS, VT, AOB, TSEQ, 64, TSEQ, TSEQ, TSEQ, CDIM,
            (long)TSEQ * TSEQ, (long)64 * TSEQ, 8, (long)TSEQ * CDIM, 64);
        // H += AOB @ o_w^T
        gemm_f32<64,64,true,true,false,false><<<dim3(8,32,1), dim3(256), 0, stream>>>(
            AOB, owl, H, BT, CDIM, CDIM, CDIM, CDIM, CDIM, 0, 0, 1, 0, 0);
        // MoE: routing + ffn-norm in one kernel
        route_k<<<dim3(BT), dim3(256), 0, stream>>>(
            H, fnw + l * CDIM, gw + (long)l * NEXP * CDIM, COMB, XN);
        gemm_f32<128,128,true,false,false,false><<<dim3(4,16,8), dim3(256), 0, stream>>>(
            XN, ewl, AOUT, BT, CDIM, CDIM, CDIM, CDIM, CDIM,
            0, (long)CDIM * CDIM, 1, (long)BT * CDIM, 0);
        combine_k<<<dim3(BT), dim3(256), 0, stream>>>(H, AOUT, COMB);
    }

    // ---- final projection: bf16 path ----
    unsigned short* OWB = (unsigned short*)SS;   // SS dead; reuse (32.8 MB)
    unsigned short* XNB = (unsigned short*)XN;   // XN dead; reuse (2 MB)
    rmsbf_k<<<dim3(BT), dim3(256), 0, stream>>>(H, finw, XNB);
    cvtw_k<<<dim3((NVOC * CDIM) / (256 * 8)), dim3(256), 0, stream>>>(outw, OWB);
    gemm_vocab<<<dim3(4000), dim3(256), 0, stream>>>((const bf16*)XNB, (const bf16*)OWB, out);
}